// Round 3
// baseline (817.649 us; speedup 1.0000x reference)
//
#include <hip/hip_runtime.h>

#define NROWS 32768   // B*T
#define PD    512     // P_DIM
#define NCB   8       // NC
#define CSZ   256     // CS
#define TOTD  2048    // TOT
#define SIN   1792    // SELF_IN / SELF_OUT

typedef float floatx4  __attribute__((ext_vector_type(4)));
typedef float floatx16 __attribute__((ext_vector_type(16)));
typedef int   intx4    __attribute__((ext_vector_type(4)));
typedef int   intx8    __attribute__((ext_vector_type(8)));

__device__ __forceinline__ float bf2f(unsigned int h) {
    return __uint_as_float(h << 16);
}
__device__ __forceinline__ unsigned short f2bf(float f) {
    unsigned int u = __float_as_uint(f);
    u += 0x7FFFu + ((u >> 16) & 1u);
    return (unsigned short)(u >> 16);
}
// f32 -> fp8 e4m3 (single value, RNE, saturating)
__device__ __forceinline__ unsigned char f2fp8(float v) {
    int p = __builtin_amdgcn_cvt_pk_fp8_f32(v, v, 0, false);
    return (unsigned char)(p & 0xFF);
}

// async global->LDS, 16B per lane; LDS dest = wave-uniform base + lane*16
__device__ __forceinline__ void gload16(const unsigned char* g, unsigned char* l) {
    __builtin_amdgcn_global_load_lds(
        (const __attribute__((address_space(1))) void*)g,
        (__attribute__((address_space(3))) void*)l, 16, 0, 0);
}

// ---------------- f32 -> fp8 conversion (8 elems/thread) ----------------
__global__ __launch_bounds__(256) void k_cvt8(const float* __restrict__ in,
                                              unsigned char* __restrict__ out,
                                              float scale, int n8) {
    int i = blockIdx.x * 256 + threadIdx.x;
    if (i >= n8) return;
    float4 a = ((const float4*)in)[2 * i];
    float4 b = ((const float4*)in)[2 * i + 1];
    int p0 = __builtin_amdgcn_cvt_pk_fp8_f32(a.x * scale, a.y * scale, 0, false);
    p0     = __builtin_amdgcn_cvt_pk_fp8_f32(a.z * scale, a.w * scale, p0, true);
    int p1 = __builtin_amdgcn_cvt_pk_fp8_f32(b.x * scale, b.y * scale, 0, false);
    p1     = __builtin_amdgcn_cvt_pk_fp8_f32(b.z * scale, b.w * scale, p1, true);
    int2 o; o.x = p0; o.y = p1;
    ((int2*)out)[i] = o;
}

// -------- transpose linear_self (1792x1792) f32 -> bf16, LSTb[in][out] --------
__global__ __launch_bounds__(256) void k_tb(const float* __restrict__ in,
                                            unsigned short* __restrict__ out) {
    __shared__ float t[32][33];
    int bx = blockIdx.x * 32, by = blockIdx.y * 32;
    int tx = threadIdx.x & 31, ty = threadIdx.x >> 5;
#pragma unroll
    for (int j = 0; j < 32; j += 8)
        t[ty + j][tx] = in[(size_t)(by + ty + j) * SIN + bx + tx];
    __syncthreads();
#pragma unroll
    for (int j = 0; j < 32; j += 8)
        out[(size_t)(bx + ty + j) * SIN + by + tx] = f2bf(t[tx][ty + j]);
}

// LDS layout per 8KB buffer (K=64 slab of 128 rows):
//   [tile T=row>>5 (4)][granule g (64)][32B]  byte = T*2048 + g*32
//   granule g holds row = T*32 + (sigma(g)&31), k bytes (g>>5)*32 .. +31,
//   where sigma(g) = g ^ ((g&12)>>2)  (involution; bank-swizzle so the
//   read pattern lane->granule sigma(lane) lands bits[6:5] ^= lane[3:2]
//   => perfect 2-way (free) instead of 4-way conflicts).
// Staging (gload16 writes lane i at wavebase + i*16):
//   wave w, call c: tile (c*2 + (w>>1)), granule g=(w&1)*32+(i>>1), half i&1
//   => source row = (w>>1)*32 + sigma32(i>>1) (+64 for c=1),
//      koff = (w&1)*32 + (i&1)*16,  sigma32(x) = x ^ ((x&12)>>2).
// Read: lane l loads intx8 at tilebase + ((l<<5) ^ ((l&12)<<3)) (two b128).
// Pipeline: TRIPLE buffer; loads for buf i issued at iter i-2; waited with
// vmcnt(4) (own newest prefetch stays in flight across the raw s_barrier).
//
// MX-scaled MFMA 32x32x64 (identity scales 0x7F = 2^0):
//   A/B fragment: lane l -> row/col = l&31, k = (l>>5)*32 + byte(0..31)
//   C/D: col = l&31, row = (r&3) + 8*(r>>2) + 4*(l>>5), r in [0,16).
//
// Occupancy: amdgpu_waves_per_eu(2,3) — max=3 stops the allocator from
// targeting 4 waves/EU (128 regs) with per-iteration spills (round-2: 846MB
// of scratch writes); target 3 waves/EU (~170 regs) fits the ~140-reg need.

// ---------------- GEMM1 (fp8): Hraw8 = fp8(8 * (pred @ W1^T + b1)) ----------------
__global__ __launch_bounds__(256) __attribute__((amdgpu_waves_per_eu(2, 3)))
void k_gemm1(const unsigned char* __restrict__ A,
             const unsigned char* __restrict__ Bw,
             const float* __restrict__ bias,
             unsigned char* __restrict__ Out) {
    const int K = PD;
    __shared__ __align__(16) unsigned char As[3 * 8192];
    __shared__ __align__(16) unsigned char Bs[3 * 8192];

    const int tid  = threadIdx.x;
    const int lane = tid & 63;
    const int wave = tid >> 6;
    const int wm = (wave >> 1) << 6;
    const int wn = (wave & 1) << 6;
    const int bid  = blockIdx.x;
    const int row0 = (bid & 255) << 7;
    const int col0 = (bid >> 8) << 7;

    floatx16 acc[2][2] = {};

    const int lh    = lane >> 1;
    const int srow  = ((wave >> 1) << 5) + (lh ^ ((lh & 12) >> 2));
    const int skoff = ((wave & 1) << 5) + ((lane & 1) << 4);
    const unsigned char* Ag  = A  + (size_t)(row0 + srow) * K + skoff;
    const unsigned char* Ag2 = Ag + (size_t)64 * K;
    const unsigned char* Bg  = Bw + (size_t)(col0 + srow) * K + skoff;
    const unsigned char* Bg2 = Bg + (size_t)64 * K;
    unsigned char* Al = As + wave * 1024;
    unsigned char* Bl = Bs + wave * 1024;

    // prologue: stage buffers 0 and 1
    gload16(Ag,        Al);
    gload16(Ag2,       Al + 4096);
    gload16(Bg,        Bl);
    gload16(Bg2,       Bl + 4096);
    gload16(Ag + 64,   Al + 8192);
    gload16(Ag2 + 64,  Al + 8192 + 4096);
    gload16(Bg + 64,   Bl + 8192);
    gload16(Bg2 + 64,  Bl + 8192 + 4096);

    const int ro = (lane << 5) ^ ((lane & 12) << 3);

    auto compute = [&](int cbuf) {
        const unsigned char* Ab = As + cbuf * 8192 + ((wm >> 5) << 11) + ro;
        const unsigned char* Bb = Bs + cbuf * 8192 + ((wn >> 5) << 11) + ro;
        intx8 a0 = *(const intx8*)Ab;
        intx8 b0 = *(const intx8*)Bb;
        intx8 a1 = *(const intx8*)(Ab + 2048);
        intx8 b1 = *(const intx8*)(Bb + 2048);
        acc[0][0] = __builtin_amdgcn_mfma_scale_f32_32x32x64_f8f6f4(
            a0, b0, acc[0][0], 0, 0, 0, 0x7F7F7F7F, 0, 0x7F7F7F7F);
        acc[1][0] = __builtin_amdgcn_mfma_scale_f32_32x32x64_f8f6f4(
            a1, b0, acc[1][0], 0, 0, 0, 0x7F7F7F7F, 0, 0x7F7F7F7F);
        acc[0][1] = __builtin_amdgcn_mfma_scale_f32_32x32x64_f8f6f4(
            a0, b1, acc[0][1], 0, 0, 0, 0x7F7F7F7F, 0, 0x7F7F7F7F);
        acc[1][1] = __builtin_amdgcn_mfma_scale_f32_32x32x64_f8f6f4(
            a1, b1, acc[1][1], 0, 0, 0, 0x7F7F7F7F, 0, 0x7F7F7F7F);
    };

    const int NI = K / 64;   // 8
    int cb = 0, nb = 2;
    for (int i = 0; i < NI - 1; ++i) {
        asm volatile("s_waitcnt vmcnt(4)" ::: "memory");
        asm volatile("s_barrier" ::: "memory");
        if (i + 2 < NI) {
            const int k0 = (i + 2) * 64;
            gload16(Ag + k0,  Al + nb * 8192);
            gload16(Ag2 + k0, Al + nb * 8192 + 4096);
            gload16(Bg + k0,  Bl + nb * 8192);
            gload16(Bg2 + k0, Bl + nb * 8192 + 4096);
        }
        compute(cb);
        cb = (cb + 1 == 3) ? 0 : cb + 1;
        nb = (nb + 1 == 3) ? 0 : nb + 1;
    }
    asm volatile("s_waitcnt vmcnt(0)" ::: "memory");
    asm volatile("s_barrier" ::: "memory");
    compute(cb);

    // epilogue: hidden = acc/16 + b1; store fp8(8*hidden)
    const int l31  = lane & 31;
    const int half = lane >> 5;
#pragma unroll
    for (int mt = 0; mt < 2; ++mt) {
#pragma unroll
        for (int nt = 0; nt < 2; ++nt) {
            const int col = col0 + wn + nt * 32 + l31;
            const float bcol = bias[col];
#pragma unroll
            for (int r = 0; r < 16; ++r) {
                const int row = row0 + wm + mt * 32 + (r & 3) + ((r >> 2) << 3) + (half << 2);
                float h = acc[mt][nt][r] * 0.0625f + bcol;
                Out[(size_t)row * TOTD + col] = f2fp8(h * 8.f);
            }
        }
    }
}

// -------- fused: self-gather + relu + LayerNorm; fp8 in (x8) -> fp8 out (x8) --------
__global__ __launch_bounds__(256) void k_ln(const unsigned char* __restrict__ Hraw8,
                                            unsigned char* __restrict__ H8,
                                            const unsigned short* __restrict__ LSTb,
                                            const int* __restrict__ idx,
                                            const float* __restrict__ gamma,
                                            const float* __restrict__ beta) {
    const int row = blockIdx.x;
    const int tid = threadIdx.x;
    __shared__ int sidx[8];
    __shared__ float ws4[4], wss4[4];
    if (tid < 8) sidx[tid] = idx[(size_t)row * NCB + tid];

    uint2 w = ((const uint2*)(Hraw8 + (size_t)row * TOTD))[tid];
    float x[8];
    x[0] = __builtin_amdgcn_cvt_f32_fp8(w.x, 0) * 0.125f;
    x[1] = __builtin_amdgcn_cvt_f32_fp8(w.x, 1) * 0.125f;
    x[2] = __builtin_amdgcn_cvt_f32_fp8(w.x, 2) * 0.125f;
    x[3] = __builtin_amdgcn_cvt_f32_fp8(w.x, 3) * 0.125f;
    x[4] = __builtin_amdgcn_cvt_f32_fp8(w.y, 0) * 0.125f;
    x[5] = __builtin_amdgcn_cvt_f32_fp8(w.y, 1) * 0.125f;
    x[6] = __builtin_amdgcn_cvt_f32_fp8(w.y, 2) * 0.125f;
    x[7] = __builtin_amdgcn_cvt_f32_fp8(w.y, 3) * 0.125f;
    __syncthreads();

    const int gt = tid >> 5;
#pragma unroll
    for (int c = 0; c < 7; ++c) {
        if (c < gt) {
            int ic = sidx[c];
            if (ic >= 0) {
                uint4 v = *(const uint4*)(LSTb + (size_t)(c * CSZ + ic) * SIN + (tid * 8 - CSZ));
                x[0] += bf2f(v.x & 0xFFFF); x[1] += bf2f(v.x >> 16);
                x[2] += bf2f(v.y & 0xFFFF); x[3] += bf2f(v.y >> 16);
                x[4] += bf2f(v.z & 0xFFFF); x[5] += bf2f(v.z >> 16);
                x[6] += bf2f(v.w & 0xFFFF); x[7] += bf2f(v.w >> 16);
            }
        }
    }
#pragma unroll
    for (int e = 0; e < 8; ++e) x[e] = fmaxf(x[e], 0.f);

    float s = 0.f, ss = 0.f;
#pragma unroll
    for (int e = 0; e < 8; ++e) { s += x[e]; ss += x[e] * x[e]; }
#pragma unroll
    for (int o = 32; o; o >>= 1) { s += __shfl_xor(s, o); ss += __shfl_xor(ss, o); }
    if ((tid & 63) == 0) { ws4[tid >> 6] = s; wss4[tid >> 6] = ss; }
    __syncthreads();
    s  = ws4[0] + ws4[1] + ws4[2] + ws4[3];
    ss = wss4[0] + wss4[1] + wss4[2] + wss4[3];
    const float mu = s * (1.f / TOTD);
    const float var = ss * (1.f / TOTD) - mu * mu;
    const float rstd = rsqrtf(var + 1e-5f);
    float y[8];
#pragma unroll
    for (int e = 0; e < 8; ++e) {
        int col = tid * 8 + e;
        y[e] = ((x[e] - mu) * rstd * gamma[col] + beta[col]) * 8.f;   // H scale 8
    }
    int p0 = __builtin_amdgcn_cvt_pk_fp8_f32(y[0], y[1], 0, false);
    p0     = __builtin_amdgcn_cvt_pk_fp8_f32(y[2], y[3], p0, true);
    int p1 = __builtin_amdgcn_cvt_pk_fp8_f32(y[4], y[5], 0, false);
    p1     = __builtin_amdgcn_cvt_pk_fp8_f32(y[6], y[7], p1, true);
    int2 o; o.x = p0; o.y = p1;
    ((int2*)(H8 + (size_t)row * TOTD))[tid] = o;
}

// ------- GEMM2 (fp8): 128x128 tile, triple-buffer pipeline + partial-softmax epilogue -------
__global__ __launch_bounds__(256) __attribute__((amdgpu_waves_per_eu(2, 3)))
void k_gemm2(const unsigned char* __restrict__ H,
             const unsigned char* __restrict__ W2,
             const float* __restrict__ b2,
             const int* __restrict__ idx,
             float* __restrict__ pm_,
             float* __restrict__ ps_,
             float* __restrict__ pt_) {
    const int K = TOTD;
    __shared__ __align__(16) unsigned char As[3 * 8192];
    __shared__ __align__(16) unsigned char Bs[3 * 8192];
    __shared__ int tidx[128];

    const int tid  = threadIdx.x;
    const int lane = tid & 63;
    const int wave = tid >> 6;
    const int wm = (wave >> 1) << 6;
    const int wn = (wave & 1) << 6;
    const int bid  = blockIdx.x;
    const int row0 = (bid & 255) << 7;
    const int col0 = (bid >> 8) << 7;
    const int g    = col0 >> 8;

    floatx16 acc[2][2] = {};

    const int lh    = lane >> 1;
    const int srow  = ((wave >> 1) << 5) + (lh ^ ((lh & 12) >> 2));
    const int skoff = ((wave & 1) << 5) + ((lane & 1) << 4);
    const unsigned char* Ag  = H  + (size_t)(row0 + srow) * K + skoff;
    const unsigned char* Ag2 = Ag + (size_t)64 * K;
    const unsigned char* Bg  = W2 + (size_t)(col0 + srow) * K + skoff;
    const unsigned char* Bg2 = Bg + (size_t)64 * K;
    unsigned char* Al = As + wave * 1024;
    unsigned char* Bl = Bs + wave * 1024;

    if (tid < 128) tidx[tid] = idx[(size_t)(row0 + tid) * NCB + g];

    gload16(Ag,        Al);
    gload16(Ag2,       Al + 4096);
    gload16(Bg,        Bl);
    gload16(Bg2,       Bl + 4096);
    gload16(Ag + 64,   Al + 8192);
    gload16(Ag2 + 64,  Al + 8192 + 4096);
    gload16(Bg + 64,   Bl + 8192);
    gload16(Bg2 + 64,  Bl + 8192 + 4096);

    const int ro = (lane << 5) ^ ((lane & 12) << 3);

    auto compute = [&](int cbuf) {
        const unsigned char* Ab = As + cbuf * 8192 + ((wm >> 5) << 11) + ro;
        const unsigned char* Bb = Bs + cbuf * 8192 + ((wn >> 5) << 11) + ro;
        intx8 a0 = *(const intx8*)Ab;
        intx8 b0 = *(const intx8*)Bb;
        intx8 a1 = *(const intx8*)(Ab + 2048);
        intx8 b1 = *(const intx8*)(Bb + 2048);
        acc[0][0] = __builtin_amdgcn_mfma_scale_f32_32x32x64_f8f6f4(
            a0, b0, acc[0][0], 0, 0, 0, 0x7F7F7F7F, 0, 0x7F7F7F7F);
        acc[1][0] = __builtin_amdgcn_mfma_scale_f32_32x32x64_f8f6f4(
            a1, b0, acc[1][0], 0, 0, 0, 0x7F7F7F7F, 0, 0x7F7F7F7F);
        acc[0][1] = __builtin_amdgcn_mfma_scale_f32_32x32x64_f8f6f4(
            a0, b1, acc[0][1], 0, 0, 0, 0x7F7F7F7F, 0, 0x7F7F7F7F);
        acc[1][1] = __builtin_amdgcn_mfma_scale_f32_32x32x64_f8f6f4(
            a1, b1, acc[1][1], 0, 0, 0, 0x7F7F7F7F, 0, 0x7F7F7F7F);
    };

    const int NI = K / 64;   // 32
    int cb = 0, nb = 2;
    for (int i = 0; i < NI - 1; ++i) {
        asm volatile("s_waitcnt vmcnt(4)" ::: "memory");
        asm volatile("s_barrier" ::: "memory");
        if (i + 2 < NI) {
            const int k0 = (i + 2) * 64;
            gload16(Ag + k0,  Al + nb * 8192);
            gload16(Ag2 + k0, Al + nb * 8192 + 4096);
            gload16(Bg + k0,  Bl + nb * 8192);
            gload16(Bg2 + k0, Bl + nb * 8192 + 4096);
        }
        compute(cb);
        cb = (cb + 1 == 3) ? 0 : cb + 1;
        nb = (nb + 1 == 3) ? 0 : nb + 1;
    }
    asm volatile("s_waitcnt vmcnt(0)" ::: "memory");
    asm volatile("s_barrier" ::: "memory");
    compute(cb);

    // ---- epilogue: per-row partials over this wave's 64-col window ----
    const int l31  = lane & 31;
    const int half = lane >> 5;
    const int slot = (col0 + wn) >> 6;   // 0..31
    const int coff = (col0 & 255) + wn;
    float bcol[2];
#pragma unroll
    for (int nt = 0; nt < 2; ++nt) bcol[nt] = b2[col0 + wn + nt * 32 + l31];

#pragma unroll
    for (int mt = 0; mt < 2; ++mt) {
#pragma unroll
        for (int r = 0; r < 16; ++r) {
            const int lrow = wm + mt * 32 + (r & 3) + ((r >> 2) << 3) + (half << 2);
            const int ic   = tidx[lrow];
            const int tloc = ic - coff;
            float v0 = acc[mt][0][r] * 0.0078125f + bcol[0];
            float v1 = acc[mt][1][r] * 0.0078125f + bcol[1];
            float mm = fmaxf(v0, v1), tv = 0.f;
            if (ic >= 0) {
                if (l31 == tloc)      tv += v0;
                if (l31 + 32 == tloc) tv += v1;
            }
#pragma unroll
            for (int o = 1; o < 32; o <<= 1) mm = fmaxf(mm, __shfl_xor(mm, o));
            float sv = __expf(v0 - mm) + __expf(v1 - mm);
#pragma unroll
            for (int o = 1; o < 32; o <<= 1) { sv += __shfl_xor(sv, o); tv += __shfl_xor(tv, o); }
            if (l31 == 0) {
                const int row = row0 + lrow;
                pm_[(size_t)slot * NROWS + row] = mm;
                ps_[(size_t)slot * NROWS + row] = sv;
                pt_[(size_t)slot * NROWS + row] = tv;
            }
        }
    }
}

// ------- combine: merge 4 slots per (row, group), accumulate logprob + count -------
__global__ __launch_bounds__(256) void k_comb(const float* __restrict__ pm_,
                                              const float* __restrict__ ps_,
                                              const float* __restrict__ pt_,
                                              const int* __restrict__ idx,
                                              float* __restrict__ out) {
    const int i   = blockIdx.x * 256 + threadIdx.x;
    const int row = i & (NROWS - 1);
    const int g   = i >> 15;
    const int ic  = idx[(size_t)row * NCB + g];
    float lp = 0.f, cnt = 0.f;
    if (ic >= 0) {
        const size_t b = (size_t)(g * 4) * NROWS + row;
        float m0 = pm_[b], m1 = pm_[b + NROWS], m2 = pm_[b + 2 * NROWS], m3 = pm_[b + 3 * NROWS];
        float mm = fmaxf(fmaxf(m0, m1), fmaxf(m2, m3));
        float Z = ps_[b] * __expf(m0 - mm) + ps_[b + NROWS] * __expf(m1 - mm)
                + ps_[b + 2 * NROWS] * __expf(m2 - mm) + ps_[b + 3 * NROWS] * __expf(m3 - mm);
        float t = pt_[b] + pt_[b + NROWS] + pt_[b + 2 * NROWS] + pt_[b + 3 * NROWS];
        lp = t - (mm + __logf(Z));
        cnt = 1.f;
    }
#pragma unroll
    for (int o = 1; o < 64; o <<= 1) { lp += __shfl_xor(lp, o); cnt += __shfl_xor(cnt, o); }
    __shared__ float wred[8];
    const int lane = threadIdx.x & 63, wave = threadIdx.x >> 6;
    if (lane == 0) { wred[wave] = lp; wred[4 + wave] = cnt; }
    __syncthreads();
    if (threadIdx.x == 0) {
        atomicAdd(&out[0], wred[0] + wred[1] + wred[2] + wred[3]);
        atomicAdd(&out[1], wred[4] + wred[5] + wred[6] + wred[7]);
    }
}

extern "C" void kernel_launch(void* const* d_in, const int* in_sizes, int n_in,
                              void* d_out, int out_size, void* d_ws, size_t ws_size,
                              hipStream_t stream) {
    const float* predictor = (const float*)d_in[0];
    const int*   cbidx     = (const int*)d_in[1];
    const float* W1        = (const float*)d_in[2];
    const float* b1        = (const float*)d_in[3];
    const float* LS        = (const float*)d_in[4];
    const float* gamma     = (const float*)d_in[5];
    const float* beta      = (const float*)d_in[6];
    const float* W2        = (const float*)d_in[7];
    const float* b2        = (const float*)d_in[8];
    float* out = (float*)d_out;

    char* ws = (char*)d_ws;
    size_t off = 0;
    auto alloc = [&](size_t bytes) {
        char* p = ws + off;
        off += (bytes + 255) & ~(size_t)255;
        return p;
    };
    unsigned char* Hraw8 = (unsigned char*)alloc((size_t)NROWS * TOTD);   // dead after k_ln -> pm/ps/pt alias
    unsigned char* R2    = (unsigned char*)alloc((size_t)NROWS * TOTD);   // pred8+W1_8, then H8
    unsigned char* W2_8  = (unsigned char*)alloc((size_t)TOTD * TOTD);
    unsigned short* LSTb = (unsigned short*)alloc((size_t)SIN * SIN * 2);

    unsigned char* pred8 = R2;
    unsigned char* W1_8  = R2 + (size_t)NROWS * PD;
    unsigned char* H8    = R2;
    float* pm_ = (float*)Hraw8;
    float* ps_ = pm_ + (size_t)32 * NROWS;
    float* pt_ = ps_ + (size_t)32 * NROWS;

    hipMemsetAsync(d_out, 0, 2 * sizeof(float), stream);

    k_cvt8<<<NROWS * PD / 8 / 256, 256, 0, stream>>>(predictor, pred8, 1.f, NROWS * PD / 8);
    k_cvt8<<<TOTD * PD / 8 / 256, 256, 0, stream>>>(W1, W1_8, 16.f, TOTD * PD / 8);
    k_cvt8<<<TOTD * TOTD / 8 / 256, 256, 0, stream>>>(W2, W2_8, 16.f, TOTD * TOTD / 8);
    k_tb<<<dim3(SIN / 32, SIN / 32), 256, 0, stream>>>(LS, LSTb);

    k_gemm1<<<16 * 256, 256, 0, stream>>>(pred8, W1_8, b1, Hraw8);
    k_ln<<<NROWS, 256, 0, stream>>>(Hraw8, H8, LSTb, cbidx, gamma, beta);
    k_gemm2<<<16 * 256, 256, 0, stream>>>(H8, W2_8, b2, cbidx, pm_, ps_, pt_);
    k_comb<<<NROWS * NCB / 256, 256, 0, stream>>>(pm_, ps_, pt_, cbidx, out);
}

// Round 4
// 557.865 us; speedup vs baseline: 1.4657x; 1.4657x over previous
//
#include <hip/hip_runtime.h>

#define NROWS 32768   // B*T
#define PD    512     // P_DIM
#define NCB   8       // NC
#define CSZ   256     // CS
#define TOTD  2048    // TOT
#define SIN   1792    // SELF_IN / SELF_OUT

typedef float floatx4  __attribute__((ext_vector_type(4)));
typedef float floatx16 __attribute__((ext_vector_type(16)));
typedef int   intx4    __attribute__((ext_vector_type(4)));
typedef int   intx8    __attribute__((ext_vector_type(8)));

__device__ __forceinline__ float bf2f(unsigned int h) {
    return __uint_as_float(h << 16);
}
__device__ __forceinline__ unsigned short f2bf(float f) {
    unsigned int u = __float_as_uint(f);
    u += 0x7FFFu + ((u >> 16) & 1u);
    return (unsigned short)(u >> 16);
}
// f32 -> fp8 e4m3 (single value, RNE, saturating)
__device__ __forceinline__ unsigned char f2fp8(float v) {
    int p = __builtin_amdgcn_cvt_pk_fp8_f32(v, v, 0, false);
    return (unsigned char)(p & 0xFF);
}

// async global->LDS, 16B per lane; LDS dest = wave-uniform base + lane*16
__device__ __forceinline__ void gload16(const unsigned char* g, unsigned char* l) {
    __builtin_amdgcn_global_load_lds(
        (const __attribute__((address_space(1))) void*)g,
        (__attribute__((address_space(3))) void*)l, 16, 0, 0);
}

// MFMA 32x32x64 f8f6f4, fp8 A/B, acc pinned to AGPRs ("a" constraint).
// Non-scaled opcode (cbsz=blgp=0 => e4m3 x e4m3), numerically identical to the
// identity-scaled builtin but keeps the 64 acc regs out of the arch-VGPR
// budget (rounds 2/3: arch cap 128 -> ~6 dwords respilled per K-iter = 846MB
// of scratch traffic; this was the whole regression).
#define MFMA64(ACC, A, B)                                                     \
    asm volatile("v_mfma_f32_32x32x64_f8f6f4 %0, %1, %2, %0"                  \
                 : "+a"(ACC) : "v"(A), "v"(B))

// ---------------- f32 -> fp8 conversion (8 elems/thread) ----------------
__global__ __launch_bounds__(256) void k_cvt8(const float* __restrict__ in,
                                              unsigned char* __restrict__ out,
                                              float scale, int n8) {
    int i = blockIdx.x * 256 + threadIdx.x;
    if (i >= n8) return;
    float4 a = ((const float4*)in)[2 * i];
    float4 b = ((const float4*)in)[2 * i + 1];
    int p0 = __builtin_amdgcn_cvt_pk_fp8_f32(a.x * scale, a.y * scale, 0, false);
    p0     = __builtin_amdgcn_cvt_pk_fp8_f32(a.z * scale, a.w * scale, p0, true);
    int p1 = __builtin_amdgcn_cvt_pk_fp8_f32(b.x * scale, b.y * scale, 0, false);
    p1     = __builtin_amdgcn_cvt_pk_fp8_f32(b.z * scale, b.w * scale, p1, true);
    int2 o; o.x = p0; o.y = p1;
    ((int2*)out)[i] = o;
}

// -------- transpose linear_self (1792x1792) f32 -> bf16, LSTb[in][out] --------
__global__ __launch_bounds__(256) void k_tb(const float* __restrict__ in,
                                            unsigned short* __restrict__ out) {
    __shared__ float t[32][33];
    int bx = blockIdx.x * 32, by = blockIdx.y * 32;
    int tx = threadIdx.x & 31, ty = threadIdx.x >> 5;
#pragma unroll
    for (int j = 0; j < 32; j += 8)
        t[ty + j][tx] = in[(size_t)(by + ty + j) * SIN + bx + tx];
    __syncthreads();
#pragma unroll
    for (int j = 0; j < 32; j += 8)
        out[(size_t)(bx + ty + j) * SIN + by + tx] = f2bf(t[tx][ty + j]);
}

// LDS layout per 8KB buffer (K=64 slab of 128 rows):
//   [tile T=row>>5 (4)][granule g (64)][32B]  byte = T*2048 + g*32
//   granule g holds row = T*32 + (sigma(g)&31), k bytes (g>>5)*32 .. +31,
//   sigma(g) = g ^ ((g&12)>>2)  (involution, mirrored on both sides).
// Staging (gload16 writes lane i at wavebase + i*16):
//   wave w, call c: tile (c*2 + (w>>1)), granule g=(w&1)*32+(i>>1), half i&1
//   => source row = (w>>1)*32 + sigma32(i>>1) (+64 for c=1),
//      koff = (w&1)*32 + (i&1)*16,  sigma32(x) = x ^ ((x&12)>>2).
// Read: lane l loads intx8 at tilebase + ((l<<5) ^ ((l&12)<<3)) (two b128).
// Pipeline: TRIPLE buffer; loads for buf i issued at iter i-2; waited with
// vmcnt(4) (own newest prefetch stays in flight across the raw s_barrier).
//
// MFMA 32x32x64 fragment: lane l -> row/col = l&31, k = (l>>5)*32 + byte.
// C/D: col = l&31, row = (r&3) + 8*(r>>2) + 4*(l>>5), r in [0,16).

// ---------------- GEMM1 (fp8): Hraw8 = fp8(8 * (pred @ W1^T + b1)) ----------------
__global__ __launch_bounds__(256)
void k_gemm1(const unsigned char* __restrict__ A,
             const unsigned char* __restrict__ Bw,
             const float* __restrict__ bias,
             unsigned char* __restrict__ Out) {
    const int K = PD;
    __shared__ __align__(16) unsigned char As[3 * 8192];
    __shared__ __align__(16) unsigned char Bs[3 * 8192];

    const int tid  = threadIdx.x;
    const int lane = tid & 63;
    const int wave = tid >> 6;
    const int wm = (wave >> 1) << 6;
    const int wn = (wave & 1) << 6;
    const int bid  = blockIdx.x;
    const int row0 = (bid & 255) << 7;
    const int col0 = (bid >> 8) << 7;

    floatx16 acc00 = 0.f, acc01 = 0.f, acc10 = 0.f, acc11 = 0.f;

    const int lh    = lane >> 1;
    const int srow  = ((wave >> 1) << 5) + (lh ^ ((lh & 12) >> 2));
    const int skoff = ((wave & 1) << 5) + ((lane & 1) << 4);
    const unsigned char* Ag  = A  + (size_t)(row0 + srow) * K + skoff;
    const unsigned char* Ag2 = Ag + (size_t)64 * K;
    const unsigned char* Bg  = Bw + (size_t)(col0 + srow) * K + skoff;
    const unsigned char* Bg2 = Bg + (size_t)64 * K;
    unsigned char* Al = As + wave * 1024;
    unsigned char* Bl = Bs + wave * 1024;

    // prologue: stage buffers 0 and 1
    gload16(Ag,        Al);
    gload16(Ag2,       Al + 4096);
    gload16(Bg,        Bl);
    gload16(Bg2,       Bl + 4096);
    gload16(Ag + 64,   Al + 8192);
    gload16(Ag2 + 64,  Al + 8192 + 4096);
    gload16(Bg + 64,   Bl + 8192);
    gload16(Bg2 + 64,  Bl + 8192 + 4096);

    const int ro = (lane << 5) ^ ((lane & 12) << 3);

    auto compute = [&](int cbuf) {
        const unsigned char* Ab = As + cbuf * 8192 + ((wm >> 5) << 11) + ro;
        const unsigned char* Bb = Bs + cbuf * 8192 + ((wn >> 5) << 11) + ro;
        intx8 a0 = *(const intx8*)Ab;
        intx8 b0 = *(const intx8*)Bb;
        intx8 a1 = *(const intx8*)(Ab + 2048);
        intx8 b1 = *(const intx8*)(Bb + 2048);
        MFMA64(acc00, a0, b0);
        MFMA64(acc10, a1, b0);
        MFMA64(acc01, a0, b1);
        MFMA64(acc11, a1, b1);
    };

    const int NI = K / 64;   // 8
    int cb = 0, nb = 2;
    for (int i = 0; i < NI - 1; ++i) {
        asm volatile("s_waitcnt vmcnt(4)" ::: "memory");
        asm volatile("s_barrier" ::: "memory");
        if (i + 2 < NI) {
            const int k0 = (i + 2) * 64;
            gload16(Ag + k0,  Al + nb * 8192);
            gload16(Ag2 + k0, Al + nb * 8192 + 4096);
            gload16(Bg + k0,  Bl + nb * 8192);
            gload16(Bg2 + k0, Bl + nb * 8192 + 4096);
        }
        compute(cb);
        cb = (cb + 1 == 3) ? 0 : cb + 1;
        nb = (nb + 1 == 3) ? 0 : nb + 1;
    }
    asm volatile("s_waitcnt vmcnt(0)" ::: "memory");
    asm volatile("s_barrier" ::: "memory");
    compute(cb);
    asm volatile("s_nop 7\n\ts_nop 7\n\ts_nop 7" ::: "memory");  // MFMA->VALU read spacing

    // epilogue: hidden = acc/16 + b1; store fp8(8*hidden)
    const int l31  = lane & 31;
    const int half = lane >> 5;
    auto epi = [&](const floatx16& A0, const floatx16& A1, int mtoff) {
        const int col = col0 + wn + l31;
        const float bc0 = bias[col];
        const float bc1 = bias[col + 32];
#pragma unroll
        for (int r = 0; r < 16; ++r) {
            const int row = row0 + wm + mtoff + (r & 3) + ((r >> 2) << 3) + (half << 2);
            Out[(size_t)row * TOTD + col]      = f2fp8((A0[r] * 0.0625f + bc0) * 8.f);
            Out[(size_t)row * TOTD + col + 32] = f2fp8((A1[r] * 0.0625f + bc1) * 8.f);
        }
    };
    epi(acc00, acc01, 0);
    epi(acc10, acc11, 32);
}

// -------- fused: self-gather + relu + LayerNorm; fp8 in (x8) -> fp8 out (x8) --------
__global__ __launch_bounds__(256) void k_ln(const unsigned char* __restrict__ Hraw8,
                                            unsigned char* __restrict__ H8,
                                            const unsigned short* __restrict__ LSTb,
                                            const int* __restrict__ idx,
                                            const float* __restrict__ gamma,
                                            const float* __restrict__ beta) {
    const int row = blockIdx.x;
    const int tid = threadIdx.x;
    __shared__ int sidx[8];
    __shared__ float ws4[4], wss4[4];
    if (tid < 8) sidx[tid] = idx[(size_t)row * NCB + tid];

    uint2 w = ((const uint2*)(Hraw8 + (size_t)row * TOTD))[tid];
    float x[8];
    x[0] = __builtin_amdgcn_cvt_f32_fp8(w.x, 0) * 0.125f;
    x[1] = __builtin_amdgcn_cvt_f32_fp8(w.x, 1) * 0.125f;
    x[2] = __builtin_amdgcn_cvt_f32_fp8(w.x, 2) * 0.125f;
    x[3] = __builtin_amdgcn_cvt_f32_fp8(w.x, 3) * 0.125f;
    x[4] = __builtin_amdgcn_cvt_f32_fp8(w.y, 0) * 0.125f;
    x[5] = __builtin_amdgcn_cvt_f32_fp8(w.y, 1) * 0.125f;
    x[6] = __builtin_amdgcn_cvt_f32_fp8(w.y, 2) * 0.125f;
    x[7] = __builtin_amdgcn_cvt_f32_fp8(w.y, 3) * 0.125f;
    __syncthreads();

    const int gt = tid >> 5;
#pragma unroll
    for (int c = 0; c < 7; ++c) {
        if (c < gt) {
            int ic = sidx[c];
            if (ic >= 0) {
                uint4 v = *(const uint4*)(LSTb + (size_t)(c * CSZ + ic) * SIN + (tid * 8 - CSZ));
                x[0] += bf2f(v.x & 0xFFFF); x[1] += bf2f(v.x >> 16);
                x[2] += bf2f(v.y & 0xFFFF); x[3] += bf2f(v.y >> 16);
                x[4] += bf2f(v.z & 0xFFFF); x[5] += bf2f(v.z >> 16);
                x[6] += bf2f(v.w & 0xFFFF); x[7] += bf2f(v.w >> 16);
            }
        }
    }
#pragma unroll
    for (int e = 0; e < 8; ++e) x[e] = fmaxf(x[e], 0.f);

    float s = 0.f, ss = 0.f;
#pragma unroll
    for (int e = 0; e < 8; ++e) { s += x[e]; ss += x[e] * x[e]; }
#pragma unroll
    for (int o = 32; o; o >>= 1) { s += __shfl_xor(s, o); ss += __shfl_xor(ss, o); }
    if ((tid & 63) == 0) { ws4[tid >> 6] = s; wss4[tid >> 6] = ss; }
    __syncthreads();
    s  = ws4[0] + ws4[1] + ws4[2] + ws4[3];
    ss = wss4[0] + wss4[1] + wss4[2] + wss4[3];
    const float mu = s * (1.f / TOTD);
    const float var = ss * (1.f / TOTD) - mu * mu;
    const float rstd = rsqrtf(var + 1e-5f);
    float y[8];
#pragma unroll
    for (int e = 0; e < 8; ++e) {
        int col = tid * 8 + e;
        y[e] = ((x[e] - mu) * rstd * gamma[col] + beta[col]) * 8.f;   // H scale 8
    }
    int p0 = __builtin_amdgcn_cvt_pk_fp8_f32(y[0], y[1], 0, false);
    p0     = __builtin_amdgcn_cvt_pk_fp8_f32(y[2], y[3], p0, true);
    int p1 = __builtin_amdgcn_cvt_pk_fp8_f32(y[4], y[5], 0, false);
    p1     = __builtin_amdgcn_cvt_pk_fp8_f32(y[6], y[7], p1, true);
    int2 o; o.x = p0; o.y = p1;
    ((int2*)(H8 + (size_t)row * TOTD))[tid] = o;
}

// ------- GEMM2 (fp8): 128x128 tile, triple-buffer pipeline + partial-softmax epilogue -------
__global__ __launch_bounds__(256)
void k_gemm2(const unsigned char* __restrict__ H,
             const unsigned char* __restrict__ W2,
             const float* __restrict__ b2,
             const int* __restrict__ idx,
             float* __restrict__ pm_,
             float* __restrict__ ps_,
             float* __restrict__ pt_) {
    const int K = TOTD;
    __shared__ __align__(16) unsigned char As[3 * 8192];
    __shared__ __align__(16) unsigned char Bs[3 * 8192];
    __shared__ int tidx[128];

    const int tid  = threadIdx.x;
    const int lane = tid & 63;
    const int wave = tid >> 6;
    const int wm = (wave >> 1) << 6;
    const int wn = (wave & 1) << 6;
    const int bid  = blockIdx.x;
    const int row0 = (bid & 255) << 7;
    const int col0 = (bid >> 8) << 7;
    const int g    = col0 >> 8;

    floatx16 acc00 = 0.f, acc01 = 0.f, acc10 = 0.f, acc11 = 0.f;

    const int lh    = lane >> 1;
    const int srow  = ((wave >> 1) << 5) + (lh ^ ((lh & 12) >> 2));
    const int skoff = ((wave & 1) << 5) + ((lane & 1) << 4);
    const unsigned char* Ag  = H  + (size_t)(row0 + srow) * K + skoff;
    const unsigned char* Ag2 = Ag + (size_t)64 * K;
    const unsigned char* Bg  = W2 + (size_t)(col0 + srow) * K + skoff;
    const unsigned char* Bg2 = Bg + (size_t)64 * K;
    unsigned char* Al = As + wave * 1024;
    unsigned char* Bl = Bs + wave * 1024;

    if (tid < 128) tidx[tid] = idx[(size_t)(row0 + tid) * NCB + g];

    gload16(Ag,        Al);
    gload16(Ag2,       Al + 4096);
    gload16(Bg,        Bl);
    gload16(Bg2,       Bl + 4096);
    gload16(Ag + 64,   Al + 8192);
    gload16(Ag2 + 64,  Al + 8192 + 4096);
    gload16(Bg + 64,   Bl + 8192);
    gload16(Bg2 + 64,  Bl + 8192 + 4096);

    const int ro = (lane << 5) ^ ((lane & 12) << 3);

    auto compute = [&](int cbuf) {
        const unsigned char* Ab = As + cbuf * 8192 + ((wm >> 5) << 11) + ro;
        const unsigned char* Bb = Bs + cbuf * 8192 + ((wn >> 5) << 11) + ro;
        intx8 a0 = *(const intx8*)Ab;
        intx8 b0 = *(const intx8*)Bb;
        intx8 a1 = *(const intx8*)(Ab + 2048);
        intx8 b1 = *(const intx8*)(Bb + 2048);
        MFMA64(acc00, a0, b0);
        MFMA64(acc10, a1, b0);
        MFMA64(acc01, a0, b1);
        MFMA64(acc11, a1, b1);
    };

    const int NI = K / 64;   // 32
    int cb = 0, nb = 2;
    for (int i = 0; i < NI - 1; ++i) {
        asm volatile("s_waitcnt vmcnt(4)" ::: "memory");
        asm volatile("s_barrier" ::: "memory");
        if (i + 2 < NI) {
            const int k0 = (i + 2) * 64;
            gload16(Ag + k0,  Al + nb * 8192);
            gload16(Ag2 + k0, Al + nb * 8192 + 4096);
            gload16(Bg + k0,  Bl + nb * 8192);
            gload16(Bg2 + k0, Bl + nb * 8192 + 4096);
        }
        compute(cb);
        cb = (cb + 1 == 3) ? 0 : cb + 1;
        nb = (nb + 1 == 3) ? 0 : nb + 1;
    }
    asm volatile("s_waitcnt vmcnt(0)" ::: "memory");
    asm volatile("s_barrier" ::: "memory");
    compute(cb);
    asm volatile("s_nop 7\n\ts_nop 7\n\ts_nop 7" ::: "memory");  // MFMA->VALU read spacing

    // ---- epilogue: per-row partials over this wave's 64-col window ----
    const int l31  = lane & 31;
    const int half = lane >> 5;
    const int slot = (col0 + wn) >> 6;   // 0..31
    const int coff = (col0 & 255) + wn;
    const float bc0 = b2[col0 + wn + l31];
    const float bc1 = b2[col0 + wn + 32 + l31];

    auto epi = [&](const floatx16& A0, const floatx16& A1, int mtoff) {
#pragma unroll
        for (int r = 0; r < 16; ++r) {
            const int lrow = wm + mtoff + (r & 3) + ((r >> 2) << 3) + (half << 2);
            const int ic   = tidx[lrow];
            const int tloc = ic - coff;
            float v0 = A0[r] * 0.0078125f + bc0;
            float v1 = A1[r] * 0.0078125f + bc1;
            float mm = fmaxf(v0, v1), tv = 0.f;
            if (ic >= 0) {
                if (l31 == tloc)      tv += v0;
                if (l31 + 32 == tloc) tv += v1;
            }
#pragma unroll
            for (int o = 1; o < 32; o <<= 1) mm = fmaxf(mm, __shfl_xor(mm, o));
            float sv = __expf(v0 - mm) + __expf(v1 - mm);
#pragma unroll
            for (int o = 1; o < 32; o <<= 1) { sv += __shfl_xor(sv, o); tv += __shfl_xor(tv, o); }
            if (l31 == 0) {
                const int row = row0 + lrow;
                pm_[(size_t)slot * NROWS + row] = mm;
                ps_[(size_t)slot * NROWS + row] = sv;
                pt_[(size_t)slot * NROWS + row] = tv;
            }
        }
    };
    epi(acc00, acc01, 0);
    epi(acc10, acc11, 32);
}

// ------- combine: merge 4 slots per (row, group), accumulate logprob + count -------
__global__ __launch_bounds__(256) void k_comb(const float* __restrict__ pm_,
                                              const float* __restrict__ ps_,
                                              const float* __restrict__ pt_,
                                              const int* __restrict__ idx,
                                              float* __restrict__ out) {
    const int i   = blockIdx.x * 256 + threadIdx.x;
    const int row = i & (NROWS - 1);
    const int g   = i >> 15;
    const int ic  = idx[(size_t)row * NCB + g];
    float lp = 0.f, cnt = 0.f;
    if (ic >= 0) {
        const size_t b = (size_t)(g * 4) * NROWS + row;
        float m0 = pm_[b], m1 = pm_[b + NROWS], m2 = pm_[b + 2 * NROWS], m3 = pm_[b + 3 * NROWS];
        float mm = fmaxf(fmaxf(m0, m1), fmaxf(m2, m3));
        float Z = ps_[b] * __expf(m0 - mm) + ps_[b + NROWS] * __expf(m1 - mm)
                + ps_[b + 2 * NROWS] * __expf(m2 - mm) + ps_[b + 3 * NROWS] * __expf(m3 - mm);
        float t = pt_[b] + pt_[b + NROWS] + pt_[b + 2 * NROWS] + pt_[b + 3 * NROWS];
        lp = t - (mm + __logf(Z));
        cnt = 1.f;
    }
#pragma unroll
    for (int o = 1; o < 64; o <<= 1) { lp += __shfl_xor(lp, o); cnt += __shfl_xor(cnt, o); }
    __shared__ float wred[8];
    const int lane = threadIdx.x & 63, wave = threadIdx.x >> 6;
    if (lane == 0) { wred[wave] = lp; wred[4 + wave] = cnt; }
    __syncthreads();
    if (threadIdx.x == 0) {
        atomicAdd(&out[0], wred[0] + wred[1] + wred[2] + wred[3]);
        atomicAdd(&out[1], wred[4] + wred[5] + wred[6] + wred[7]);
    }
}

extern "C" void kernel_launch(void* const* d_in, const int* in_sizes, int n_in,
                              void* d_out, int out_size, void* d_ws, size_t ws_size,
                              hipStream_t stream) {
    const float* predictor = (const float*)d_in[0];
    const int*   cbidx     = (const int*)d_in[1];
    const float* W1        = (const float*)d_in[2];
    const float* b1        = (const float*)d_in[3];
    const float* LS        = (const float*)d_in[4];
    const float* gamma     = (const float*)d_in[5];
    const float* beta      = (const float*)d_in[6];
    const float* W2        = (const float*)d_in[7];
    const float* b2        = (const float*)d_in[8];
    float* out = (float*)d_out;

    char* ws = (char*)d_ws;
    size_t off = 0;
    auto alloc = [&](size_t bytes) {
        char* p = ws + off;
        off += (bytes + 255) & ~(size_t)255;
        return p;
    };
    unsigned char* Hraw8 = (unsigned char*)alloc((size_t)NROWS * TOTD);   // dead after k_ln -> pm/ps/pt alias
    unsigned char* R2    = (unsigned char*)alloc((size_t)NROWS * TOTD);   // pred8+W1_8, then H8
    unsigned char* W2_8  = (unsigned char*)alloc((size_t)TOTD * TOTD);
    unsigned short* LSTb = (unsigned short*)alloc((size_t)SIN * SIN * 2);

    unsigned char* pred8 = R2;
    unsigned char* W1_8  = R2 + (size_t)NROWS * PD;
    unsigned char* H8    = R2;
    float* pm_ = (float*)Hraw8;
    float* ps_ = pm_ + (size_t)32 * NROWS;
    float* pt_ = ps_ + (size_t)32 * NROWS;

    hipMemsetAsync(d_out, 0, 2 * sizeof(float), stream);

    k_cvt8<<<NROWS * PD / 8 / 256, 256, 0, stream>>>(predictor, pred8, 1.f, NROWS * PD / 8);
    k_cvt8<<<TOTD * PD / 8 / 256, 256, 0, stream>>>(W1, W1_8, 16.f, TOTD * PD / 8);
    k_cvt8<<<TOTD * TOTD / 8 / 256, 256, 0, stream>>>(W2, W2_8, 16.f, TOTD * TOTD / 8);
    k_tb<<<dim3(SIN / 32, SIN / 32), 256, 0, stream>>>(LS, LSTb);

    k_gemm1<<<16 * 256, 256, 0, stream>>>(pred8, W1_8, b1, Hraw8);
    k_ln<<<NROWS, 256, 0, stream>>>(Hraw8, H8, LSTb, cbidx, gamma, beta);
    k_gemm2<<<16 * 256, 256, 0, stream>>>(H8, W2_8, b2, cbidx, pm_, ps_, pt_);
    k_comb<<<NROWS * NCB / 256, 256, 0, stream>>>(pm_, ps_, pt_, cbidx, out);
}